// Round 8
// baseline (2203.934 us; speedup 1.0000x reference)
//
#include <hip/hip_runtime.h>

typedef _Float16 f16x8 __attribute__((ext_vector_type(8)));
typedef _Float16 f16x4 __attribute__((ext_vector_type(4)));
typedef _Float16 f16x2 __attribute__((ext_vector_type(2)));
typedef float    f32x4 __attribute__((ext_vector_type(4)));
typedef float    f32x2 __attribute__((ext_vector_type(2)));

#define NTRAJ  4096
#define LSTEPS 128
#define IDIM   32
#define LD     64
#define NU     256
#define MB     16
#define NBLK   (NTRAJ/MB)    // 256 blocks

// frag bases (units of 1KB frags) in d_ws; lo-set lives at +NFRAGS
#define FB_WO1 0
#define FB_WO2 32
#define FB_WU1 64
#define FB_WU2 144
#define FB_WR1 176
#define FB_WR2 256
#define FB_WN1 288
#define FB_WN2 368
#define NFRAGS 432

// LDS pitches (elements)
#define PF  68    // fp32 width-64 arrays
#define PBY 72    // f16 width-64 arrays
#define PBX 40    // f16 width-32
#define PBC 136   // f16 width-128
#define PBH 520   // f16 width-512

// opacity barrier: forces value to live in VGPRs, blocks rematerialization
#define KEEP(x) asm volatile("" : "+v"(x))

#define MFMA(a, b, c) __builtin_amdgcn_mfma_f32_16x16x32_f16((a), (b), (c), 0, 0, 0)

static __device__ __forceinline__ float sigmoid_fast(float x) {
  float t = __builtin_amdgcn_exp2f(x * -1.442695041f);
  return __builtin_amdgcn_rcpf(1.0f + t);
}
static __device__ __forceinline__ float tanh_fast(float x) {
  float t = __builtin_amdgcn_exp2f(x * -2.885390082f);
  return __builtin_amdgcn_rcpf(1.0f + t) * 2.0f - 1.0f;
}
static __device__ __forceinline__ f16x2 split2(float v) {
  _Float16 h = (_Float16)v;
  f16x2 r; r[0] = h; r[1] = (_Float16)(v - (float)h);
  return r;
}

// ---------------- weight prep: fp32 [K][N] -> f16 hi/lo A-fragment swizzle ----------------
// frag (kc, mt): lane l holds W[kc*32 + (l>>4)*8 + j][mt*16 + (l&15)]  == A[m=l&15][k=q8+j]
__global__ void prep_weights(const float* __restrict__ Wo1, const float* __restrict__ Wo2,
                             const float* __restrict__ Wu1, const float* __restrict__ Wu2,
                             const float* __restrict__ Wr1, const float* __restrict__ Wr2,
                             const float* __restrict__ Wn1, const float* __restrict__ Wn2,
                             f16x8* __restrict__ ws)
{
  int f = blockIdx.x;
  const float* W; int N; int base;
  if (f < 32)       { W = Wo1; N = 256; base = 0;   }
  else if (f < 64)  { W = Wo2; N = 64;  base = 32;  }
  else if (f < 144) { W = Wu1; N = 256; base = 64;  }
  else if (f < 176) { W = Wu2; N = 64;  base = 144; }
  else if (f < 256) { W = Wr1; N = 256; base = 176; }
  else if (f < 288) { W = Wr2; N = 64;  base = 256; }
  else if (f < 368) { W = Wn1; N = 256; base = 288; }
  else              { W = Wn2; N = 128; base = 368; }
  int fl  = f - base;
  int nts = N >> 4;
  int kc  = fl / nts;
  int nt  = fl - kc * nts;
  int l   = threadIdx.x;
  int k0  = kc * 32 + (l >> 4) * 8;
  int n   = nt * 16 + (l & 15);
  f16x8 h, lo;
#pragma unroll
  for (int j = 0; j < 8; ++j) {
    float w = W[(size_t)(k0 + j) * N + n];
    _Float16 hh = (_Float16)w;
    h[j]  = hh;
    lo[j] = (_Float16)(w - (float)hh);
  }
  ws[f * 64 + l]            = h;
  ws[(NFRAGS + f) * 64 + l] = lo;
}

// ---------------- main persistent-scan kernel: 512 threads, 8 waves ----------------
__global__ __launch_bounds__(512, 2) void vae_main(
    const float* __restrict__ data, const float* __restrict__ ts,
    const float* __restrict__ bo1, const float* __restrict__ bo2,
    const float* __restrict__ bu1, const float* __restrict__ bu2,
    const float* __restrict__ br1, const float* __restrict__ br2,
    const float* __restrict__ bn1, const float* __restrict__ bn2,
    const f16x8* WF, float* out)
{
  __shared__ __align__(16) float s_y[MB*PF], s_lv[MB*PF], s_yode[MB*PF], s_U[MB*PF];
  __shared__ __align__(16) float s_bias[1344];
  __shared__ float s_dts[LSTEPS];
  __shared__ __align__(16) _Float16 b_y[2][MB*PBY], b_lv[2][MB*PBY], b_yode[2][MB*PBY];
  __shared__ __align__(16) _Float16 b_x[2][MB*PBX], b_cc[2][MB*PBC], b_hid[2][MB*PBH];
  __shared__ __align__(16) f16x8 l_wo2[64*64];   // Wo2 frags: [0..31]=hi, [32..63]=lo

  const int tid  = threadIdx.x;
  const int lane = tid & 63;
  const int wave = tid >> 6;       // 0..7
  const int q    = lane >> 4;
  const int l16  = lane & 15;
  const int q8   = q * 8;
  const int traj0 = blockIdx.x * MB;

#define AH(base, nts, kc, mt) WF[((base) + (kc)*(nts) + (mt)) * 64 + lane]
#define AL(base, nts, kc, mt) WF[(NFRAGS + (base) + (kc)*(nts) + (mt)) * 64 + lane]
#define LDB(arr, pitch, koff) (*(const f16x8*)&(arr)[(l16)*(pitch) + (koff) + q8])

  // ---- persistent per-wave weight caches (pinned via KEEP) ----
  f16x8 cw1[8], cw4[16], cw6[16];
#pragma unroll
  for (int s = 0; s < 2; ++s)
#pragma unroll
    for (int kc = 0; kc < 2; ++kc) {
      cw1[4*s+2*kc]   = WF[(FB_WO1 + kc*16 + (wave*2+s)) * 64 + lane];
      cw1[4*s+2*kc+1] = WF[(NFRAGS + FB_WO1 + kc*16 + (wave*2+s)) * 64 + lane];
    }
  {
    int fb4 = (wave < 4) ? FB_WU2 : FB_WR2;
    int mt4 = wave & 3;
#pragma unroll
    for (int kc = 0; kc < 8; ++kc) {
      cw4[2*kc]   = WF[(fb4 + kc*4 + mt4) * 64 + lane];
      cw4[2*kc+1] = WF[(NFRAGS + fb4 + kc*4 + mt4) * 64 + lane];
      cw6[2*kc]   = WF[(FB_WN2 + kc*8 + wave) * 64 + lane];
      cw6[2*kc+1] = WF[(NFRAGS + FB_WN2 + kc*8 + wave) * 64 + lane];
    }
  }
#pragma unroll
  for (int i = 0; i < 8; ++i)  KEEP(cw1[i]);
#pragma unroll
  for (int i = 0; i < 16; ++i) { KEEP(cw4[i]); KEEP(cw6[i]); }

  // ---- stage Wo2 into LDS (64 frags x 64 lanes x 16B) ----
  for (int i = tid; i < 64*64; i += 512) {
    int idx = i >> 6, l = i & 63;
    int src = (idx < 32) ? (FB_WO2 + idx) : (NFRAGS + FB_WO2 + (idx - 32));
    l_wo2[i] = WF[src * 64 + l];
  }

  // stage biases / dts, zero state
  for (int i = tid; i < NU; i += 512) s_bias[0    + i] = bo1[i];
  if (tid < LD)                       s_bias[256  + tid] = bo2[tid];
  for (int i = tid; i < NU; i += 512) s_bias[320  + i] = bu1[i];
  if (tid < LD)                       s_bias[576  + tid] = bu2[tid];
  for (int i = tid; i < NU; i += 512) s_bias[640  + i] = br1[i];
  if (tid < LD)                       s_bias[896  + tid] = br2[tid];
  for (int i = tid; i < NU; i += 512) s_bias[960  + i] = bn1[i];
  if (tid < 2*LD)                     s_bias[1216 + tid] = bn2[tid];
  if (tid < LSTEPS-1) s_dts[tid] = (tid == 0) ? (ts[1] - ts[0]) : (ts[tid] - ts[tid+1]);
  for (int i = tid; i < MB*PF;  i += 512) { s_y[i] = 0.f; s_lv[i] = 0.f; }
  for (int i = tid; i < 2*MB*PBY; i += 512) {
    ((_Float16*)b_y)[i]  = (_Float16)0.f;
    ((_Float16*)b_lv)[i] = (_Float16)0.f;
  }
  __syncthreads();

  for (int t = 0; t < LSTEPS-1; ++t) {
    // ---- S1: hid_o = tanh(Wo1^T y + bo1); cached cw1; 2 mtiles/wave; 2-acc ILP ----
    {
      f16x8 b0h = LDB(b_y[0],PBY,0),  b0l = LDB(b_y[1],PBY,0);
      f16x8 b1h = LDB(b_y[0],PBY,32), b1l = LDB(b_y[1],PBY,32);
#pragma unroll
      for (int s = 0; s < 2; ++s) {
        f32x4 aH = {0.f,0.f,0.f,0.f}, aL = {0.f,0.f,0.f,0.f};
        aH = MFMA(cw1[4*s],   b0h, aH);
        aL = MFMA(cw1[4*s+1], b0h, aL);
        aL = MFMA(cw1[4*s],   b0l, aL);
        aH = MFMA(cw1[4*s+2], b1h, aH);
        aL = MFMA(cw1[4*s+3], b1h, aL);
        aL = MFMA(cw1[4*s+2], b1l, aL);
        f32x4 acc = aH + aL;
        int f0 = (wave*2+s)*16 + q*4;
        f32x4 bb = *(const f32x4*)&s_bias[0 + f0];
        f16x4 hv, lv4;
#pragma unroll
        for (int r = 0; r < 4; ++r) {
          f16x2 sp = split2(tanh_fast(acc[r] + bb[r]));
          hv[r] = sp[0]; lv4[r] = sp[1];
        }
        *(f16x4*)&b_hid[0][l16*PBH + f0] = hv;
        *(f16x4*)&b_hid[1][l16*PBH + f0] = lv4;
      }
    }
    __syncthreads();

    // ---- S2: yode = y + dt*(Wo2^T hid_o + bo2); waves 0-3 (Wo2 in LDS); 3-acc ILP ----
    if (wave < 4) {
      float dt = s_dts[t];
      f32x4 aA = {0.f,0.f,0.f,0.f}, aB = {0.f,0.f,0.f,0.f}, aC = {0.f,0.f,0.f,0.f};
#pragma unroll
      for (int kc = 0; kc < 8; ++kc) {
        f16x8 ah = l_wo2[(kc*4 + wave)*64 + lane];
        f16x8 al = l_wo2[(32 + kc*4 + wave)*64 + lane];
        f16x8 bhk = LDB(b_hid[0],PBH,kc*32), blk = LDB(b_hid[1],PBH,kc*32);
        aA = MFMA(ah, bhk, aA);
        aB = MFMA(al, bhk, aB);
        aC = MFMA(ah, blk, aC);
      }
      f32x4 acc = aA + aB + aC;
      int f0 = wave*16 + q*4;
      f32x4 bb = *(const f32x4*)&s_bias[256 + f0];
      f32x4 yv = *(const f32x4*)&s_y[l16*PF + f0];
      f32x4 yo;
      f16x4 hv, lv4;
#pragma unroll
      for (int r = 0; r < 4; ++r) {
        yo[r] = yv[r] + dt * (acc[r] + bb[r]);
        f16x2 sp = split2(yo[r]);
        hv[r] = sp[0]; lv4[r] = sp[1];
      }
      *(f32x4*)&s_yode[l16*PF + f0] = yo;
      *(f16x4*)&b_yode[0][l16*PBY + f0] = hv;
      *(f16x4*)&b_yode[1][l16*PBY + f0] = lv4;
    } else {
      int idx = tid - 256;                 // 0..255: 16 rows x 16 thread-cols x 2 elems
      int row = idx >> 4, c0 = (idx & 15) * 2;
      f32x2 d = *(const f32x2*)&data[(size_t)(traj0 + row) * LSTEPS * IDIM
                                     + (size_t)(t+1) * IDIM + c0];
      f16x2 s0 = split2(d[0]), s1 = split2(d[1]);
      f16x2 xh, xl;
      xh[0] = s0[0]; xl[0] = s0[1];
      xh[1] = s1[0]; xl[1] = s1[1];
      *(f16x2*)&b_x[0][row*PBX + c0] = xh;
      *(f16x2*)&b_x[1][row*PBX + c0] = xl;
    }
    __syncthreads();

    // ---- S3: hid_ur = tanh([Wu1|Wr1]^T yc + b); kc-outer, 4 mtiles, 8-acc ILP ----
    {
      f16x8 bh[5], bl[5];
      bh[0] = LDB(b_yode[0],PBY,0);  bl[0] = LDB(b_yode[1],PBY,0);
      bh[1] = LDB(b_yode[0],PBY,32); bl[1] = LDB(b_yode[1],PBY,32);
      bh[2] = LDB(b_lv[0],  PBY,0);  bl[2] = LDB(b_lv[1],  PBY,0);
      bh[3] = LDB(b_lv[0],  PBY,32); bl[3] = LDB(b_lv[1],  PBY,32);
      bh[4] = LDB(b_x[0],   PBX,0);  bl[4] = LDB(b_x[1],   PBX,0);
      int isR = wave >> 2;
      int fb  = isR ? FB_WR1 : FB_WU1;
      int mt0 = (wave & 3) * 4;
      f32x4 aH[4], aL[4];
#pragma unroll
      for (int s = 0; s < 4; ++s) {
        aH[s] = (f32x4){0.f,0.f,0.f,0.f};
        aL[s] = (f32x4){0.f,0.f,0.f,0.f};
      }
#pragma unroll
      for (int kc = 0; kc < 5; ++kc) {
#pragma unroll
        for (int s = 0; s < 4; ++s) {
          f16x8 ah = AH(fb,16,kc,mt0+s);
          f16x8 al = AL(fb,16,kc,mt0+s);
          aH[s] = MFMA(ah, bh[kc], aH[s]);
          aL[s] = MFMA(al, bh[kc], aL[s]);
          aL[s] = MFMA(ah, bl[kc], aL[s]);
        }
      }
#pragma unroll
      for (int s = 0; s < 4; ++s) {
        f32x4 acc = aH[s] + aL[s];
        int col0 = (mt0 + s)*16 + q*4;        // 0..255 within gate
        f32x4 bb = *(const f32x4*)&s_bias[(isR ? 640 : 320) + col0];
        int dcol = (isR ? 256 : 0) + col0;
        f16x4 hv, lv4;
#pragma unroll
        for (int r = 0; r < 4; ++r) {
          f16x2 sp = split2(tanh_fast(acc[r] + bb[r]));
          hv[r] = sp[0]; lv4[r] = sp[1];
        }
        *(f16x4*)&b_hid[0][l16*PBH + dcol] = hv;
        *(f16x4*)&b_hid[1][l16*PBH + dcol] = lv4;
      }
    }
    __syncthreads();

    // ---- S4: U = sig(Wu2^T hid_u), R = sig(Wr2^T hid_r); cached cw4; 3-acc; cc fused ----
    {
      int isR  = wave >> 2;
      int aofs = isR ? 256 : 0;
      f32x4 aA = {0.f,0.f,0.f,0.f}, aB = {0.f,0.f,0.f,0.f}, aC = {0.f,0.f,0.f,0.f};
#pragma unroll
      for (int kc = 0; kc < 8; ++kc) {
        f16x8 bhk = LDB(b_hid[0],PBH,aofs+kc*32), blk = LDB(b_hid[1],PBH,aofs+kc*32);
        aA = MFMA(cw4[2*kc],   bhk, aA);
        aB = MFMA(cw4[2*kc+1], bhk, aB);
        aC = MFMA(cw4[2*kc],   blk, aC);
      }
      f32x4 acc = aA + aB + aC;
      int f0 = (wave & 3)*16 + q*4;
      f32x4 bb = *(const f32x4*)&s_bias[(isR ? 896 : 576) + f0];
      if (!isR) {
        f32x4 o;
#pragma unroll
        for (int r = 0; r < 4; ++r) o[r] = sigmoid_fast(acc[r] + bb[r]);
        *(f32x4*)&s_U[l16*PF + f0] = o;
      } else {
        // R never materialized: build cc = [yode*R | lv*R] directly
        f32x4 yo = *(const f32x4*)&s_yode[l16*PF + f0];
        f32x4 lv = *(const f32x4*)&s_lv[l16*PF + f0];
        f16x4 yh, yl, lh, ll;
#pragma unroll
        for (int r = 0; r < 4; ++r) {
          float rv = sigmoid_fast(acc[r] + bb[r]);
          f16x2 sa = split2(yo[r] * rv);
          f16x2 sb = split2(lv[r] * rv);
          yh[r] = sa[0]; yl[r] = sa[1];
          lh[r] = sb[0]; ll[r] = sb[1];
        }
        *(f16x4*)&b_cc[0][l16*PBC + f0] = yh;
        *(f16x4*)&b_cc[1][l16*PBC + f0] = yl;
        *(f16x4*)&b_cc[0][l16*PBC + 64 + f0] = lh;
        *(f16x4*)&b_cc[1][l16*PBC + 64 + f0] = ll;
      }
    }
    __syncthreads();

    // ---- S5: hid_n = tanh(Wn1^T cc + bn1); kc-outer, 2 mtiles, 4-acc ILP ----
    {
      f16x8 bh[5], bl[5];
      bh[0] = LDB(b_cc[0],PBC,0);  bl[0] = LDB(b_cc[1],PBC,0);
      bh[1] = LDB(b_cc[0],PBC,32); bl[1] = LDB(b_cc[1],PBC,32);
      bh[2] = LDB(b_cc[0],PBC,64); bl[2] = LDB(b_cc[1],PBC,64);
      bh[3] = LDB(b_cc[0],PBC,96); bl[3] = LDB(b_cc[1],PBC,96);
      bh[4] = LDB(b_x[0], PBX,0);  bl[4] = LDB(b_x[1], PBX,0);
      f32x4 aH[2], aL[2];
#pragma unroll
      for (int s = 0; s < 2; ++s) {
        aH[s] = (f32x4){0.f,0.f,0.f,0.f};
        aL[s] = (f32x4){0.f,0.f,0.f,0.f};
      }
#pragma unroll
      for (int kc = 0; kc < 5; ++kc) {
#pragma unroll
        for (int s = 0; s < 2; ++s) {
          f16x8 ah = AH(FB_WN1,16,kc,wave*2+s);
          f16x8 al = AL(FB_WN1,16,kc,wave*2+s);
          aH[s] = MFMA(ah, bh[kc], aH[s]);
          aL[s] = MFMA(al, bh[kc], aL[s]);
          aL[s] = MFMA(ah, bl[kc], aL[s]);
        }
      }
#pragma unroll
      for (int s = 0; s < 2; ++s) {
        f32x4 acc = aH[s] + aL[s];
        int f0 = (wave*2+s)*16 + q*4;
        f32x4 bb = *(const f32x4*)&s_bias[960 + f0];
        f16x4 hv, lv4;
#pragma unroll
        for (int r = 0; r < 4; ++r) {
          f16x2 sp = split2(tanh_fast(acc[r] + bb[r]));
          hv[r] = sp[0]; lv4[r] = sp[1];
        }
        *(f16x4*)&b_hid[0][l16*PBH + f0] = hv;
        *(f16x4*)&b_hid[1][l16*PBH + f0] = lv4;
      }
    }
    __syncthreads();

    // ---- S6: h = Wn2^T hid_n + bn2; GRU gating + state update; cached cw6; 3-acc ----
    {
      f32x4 aA = {0.f,0.f,0.f,0.f}, aB = {0.f,0.f,0.f,0.f}, aC = {0.f,0.f,0.f,0.f};
#pragma unroll
      for (int kc = 0; kc < 8; ++kc) {
        f16x8 bhk = LDB(b_hid[0],PBH,kc*32), blk = LDB(b_hid[1],PBH,kc*32);
        aA = MFMA(cw6[2*kc],   bhk, aA);
        aB = MFMA(cw6[2*kc+1], bhk, aB);
        aC = MFMA(cw6[2*kc],   blk, aC);
      }
      f32x4 acc = aA + aB + aC;
      int f0 = wave*16 + q*4;                      // 0..127
      f32x4 bb = *(const f32x4*)&s_bias[1216 + f0];
      if (wave < 4) {
        f32x4 u  = *(const f32x4*)&s_U[l16*PF + f0];
        f32x4 yo = *(const f32x4*)&s_yode[l16*PF + f0];
        f32x4 nv;
        f16x4 hv, lv4;
#pragma unroll
        for (int r = 0; r < 4; ++r) {
          float h = acc[r] + bb[r];
          nv[r] = (1.f - u[r]) * h + u[r] * yo[r];
          f16x2 sp = split2(nv[r]);
          hv[r] = sp[0]; lv4[r] = sp[1];
        }
        *(f32x4*)&s_y[l16*PF + f0] = nv;
        *(f16x4*)&b_y[0][l16*PBY + f0] = hv;
        *(f16x4*)&b_y[1][l16*PBY + f0] = lv4;
      } else {
        int f2 = f0 - 64;
        f32x4 u  = *(const f32x4*)&s_U[l16*PF + f2];
        f32x4 lv = *(const f32x4*)&s_lv[l16*PF + f2];
        f32x4 nl;
        f16x4 hv, lv4;
#pragma unroll
        for (int r = 0; r < 4; ++r) {
          float h = fabsf(acc[r] + bb[r]);
          nl[r] = (1.f - u[r]) * h + u[r] * lv[r];
          f16x2 sp = split2(nl[r]);
          hv[r] = sp[0]; lv4[r] = sp[1];
        }
        *(f32x4*)&s_lv[l16*PF + f2] = nl;
        *(f16x4*)&b_lv[0][l16*PBY + f2] = hv;
        *(f16x4*)&b_lv[1][l16*PBY + f2] = lv4;
      }
    }
    __syncthreads();
  }

  // write outputs: (yi, yi_logvar) concatenated
  for (int i = tid; i < MB*LD; i += 512) {
    int row = i >> 6, c = i & 63;
    out[(size_t)(traj0 + row) * LD + c] = s_y[row*PF + c];
    out[(size_t)NTRAJ * LD + (size_t)(traj0 + row) * LD + c] = s_lv[row*PF + c];
  }
}

extern "C" void kernel_launch(void* const* d_in, const int* in_sizes, int n_in,
                              void* d_out, int out_size, void* d_ws, size_t ws_size,
                              hipStream_t stream) {
  const float* data = (const float*)d_in[0];
  const float* ts   = (const float*)d_in[1];
  const float* Wo1  = (const float*)d_in[2];  const float* bo1 = (const float*)d_in[3];
  const float* Wo2  = (const float*)d_in[4];  const float* bo2 = (const float*)d_in[5];
  const float* Wu1  = (const float*)d_in[6];  const float* bu1 = (const float*)d_in[7];
  const float* Wu2  = (const float*)d_in[8];  const float* bu2 = (const float*)d_in[9];
  const float* Wr1  = (const float*)d_in[10]; const float* br1 = (const float*)d_in[11];
  const float* Wr2  = (const float*)d_in[12]; const float* br2 = (const float*)d_in[13];
  const float* Wn1  = (const float*)d_in[14]; const float* bn1 = (const float*)d_in[15];
  const float* Wn2  = (const float*)d_in[16]; const float* bn2 = (const float*)d_in[17];

  prep_weights<<<NFRAGS, 64, 0, stream>>>(Wo1, Wo2, Wu1, Wu2, Wr1, Wr2, Wn1, Wn2,
                                          (f16x8*)d_ws);
  vae_main<<<NBLK, 512, 0, stream>>>(data, ts, bo1, bo2, bu1, bu2, br1, br2,
                                     bn1, bn2, (const f16x8*)d_ws, (float*)d_out);
}

// Round 9
// 1986.952 us; speedup vs baseline: 1.1092x; 1.1092x over previous
//
#include <hip/hip_runtime.h>

typedef _Float16 f16x8 __attribute__((ext_vector_type(8)));
typedef _Float16 f16x4 __attribute__((ext_vector_type(4)));
typedef _Float16 f16x2 __attribute__((ext_vector_type(2)));
typedef float    f32x4 __attribute__((ext_vector_type(4)));
typedef float    f32x2 __attribute__((ext_vector_type(2)));

#define NTRAJ  4096
#define LSTEPS 128
#define IDIM   32
#define LD     64
#define NU     256
#define MB     16
#define NBLK   (NTRAJ/MB)    // 256 blocks

// frag bases (units of 1KB frags) in d_ws; lo-set lives at +NFRAGS
#define FB_WO1 0
#define FB_WO2 32
#define FB_WU1 64
#define FB_WU2 144
#define FB_WR1 176
#define FB_WR2 256
#define FB_WN1 288
#define FB_WN2 368
#define NFRAGS 432

// LDS pitches (elements)
#define PF  68    // fp32 width-64 arrays
#define PBY 72    // f16 width-64 arrays
#define PBX 40    // f16 width-32
#define PBC 136   // f16 width-128
#define PBH 520   // f16 width-512

// opacity barrier: forces value to live in VGPRs, blocks rematerialization
#define KEEP(x) asm volatile("" : "+v"(x))

#define MFMA(a, b, c) __builtin_amdgcn_mfma_f32_16x16x32_f16((a), (b), (c), 0, 0, 0)

static __device__ __forceinline__ float sigmoid_fast(float x) {
  float t = __builtin_amdgcn_exp2f(x * -1.442695041f);
  return __builtin_amdgcn_rcpf(1.0f + t);
}
static __device__ __forceinline__ float tanh_fast(float x) {
  float t = __builtin_amdgcn_exp2f(x * -2.885390082f);
  return __builtin_amdgcn_rcpf(1.0f + t) * 2.0f - 1.0f;
}
static __device__ __forceinline__ f16x2 split2(float v) {
  _Float16 h = (_Float16)v;
  f16x2 r; r[0] = h; r[1] = (_Float16)(v - (float)h);
  return r;
}

// ---------------- weight prep: fp32 [K][N] -> f16 hi/lo A-fragment swizzle ----------------
// frag (kc, mt): lane l holds W[kc*32 + (l>>4)*8 + j][mt*16 + (l&15)]  == A[m=l&15][k=q8+j]
__global__ void prep_weights(const float* __restrict__ Wo1, const float* __restrict__ Wo2,
                             const float* __restrict__ Wu1, const float* __restrict__ Wu2,
                             const float* __restrict__ Wr1, const float* __restrict__ Wr2,
                             const float* __restrict__ Wn1, const float* __restrict__ Wn2,
                             f16x8* __restrict__ ws)
{
  int f = blockIdx.x;
  const float* W; int N; int base;
  if (f < 32)       { W = Wo1; N = 256; base = 0;   }
  else if (f < 64)  { W = Wo2; N = 64;  base = 32;  }
  else if (f < 144) { W = Wu1; N = 256; base = 64;  }
  else if (f < 176) { W = Wu2; N = 64;  base = 144; }
  else if (f < 256) { W = Wr1; N = 256; base = 176; }
  else if (f < 288) { W = Wr2; N = 64;  base = 256; }
  else if (f < 368) { W = Wn1; N = 256; base = 288; }
  else              { W = Wn2; N = 128; base = 368; }
  int fl  = f - base;
  int nts = N >> 4;
  int kc  = fl / nts;
  int nt  = fl - kc * nts;
  int l   = threadIdx.x;
  int k0  = kc * 32 + (l >> 4) * 8;
  int n   = nt * 16 + (l & 15);
  f16x8 h, lo;
#pragma unroll
  for (int j = 0; j < 8; ++j) {
    float w = W[(size_t)(k0 + j) * N + n];
    _Float16 hh = (_Float16)w;
    h[j]  = hh;
    lo[j] = (_Float16)(w - (float)hh);
  }
  ws[f * 64 + l]            = h;
  ws[(NFRAGS + f) * 64 + l] = lo;
}

// ---------------- main persistent-scan kernel: 512 threads, 8 waves ----------------
__global__ __launch_bounds__(512, 2) void vae_main(
    const float* __restrict__ data, const float* __restrict__ ts,
    const float* __restrict__ bo1, const float* __restrict__ bo2,
    const float* __restrict__ bu1, const float* __restrict__ bu2,
    const float* __restrict__ br1, const float* __restrict__ br2,
    const float* __restrict__ bn1, const float* __restrict__ bn2,
    const f16x8* WF, float* out)
{
  __shared__ __align__(16) float s_y[MB*PF], s_lv[MB*PF], s_yode[MB*PF], s_U[MB*PF];
  __shared__ __align__(16) float s_bias[1344];
  __shared__ float s_dts[LSTEPS];
  __shared__ __align__(16) _Float16 b_y[2][MB*PBY], b_lv[2][MB*PBY], b_yode[2][MB*PBY];
  __shared__ __align__(16) _Float16 b_x[2][MB*PBX], b_cc[2][MB*PBC], b_hid[2][MB*PBH];
  __shared__ __align__(16) f16x8 l_wo2[64*64];   // Wo2 frags: [0..31]=hi, [32..63]=lo

  const int tid  = threadIdx.x;
  const int lane = tid & 63;
  const int wave = tid >> 6;       // 0..7
  const int q    = lane >> 4;
  const int l16  = lane & 15;
  const int q8   = q * 8;
  const int traj0 = blockIdx.x * MB;

#define AH(base, nts, kc, mt) WF[((base) + (kc)*(nts) + (mt)) * 64 + lane]
#define AL(base, nts, kc, mt) WF[(NFRAGS + (base) + (kc)*(nts) + (mt)) * 64 + lane]
#define LDB(arr, pitch, koff) (*(const f16x8*)&(arr)[(l16)*(pitch) + (koff) + q8])

  // ---- persistent per-wave weight caches (pinned via KEEP) ----
  f16x8 cw1[8], cw4[16], cw6[16];
#pragma unroll
  for (int s = 0; s < 2; ++s)
#pragma unroll
    for (int kc = 0; kc < 2; ++kc) {
      cw1[4*s+2*kc]   = WF[(FB_WO1 + kc*16 + (wave*2+s)) * 64 + lane];
      cw1[4*s+2*kc+1] = WF[(NFRAGS + FB_WO1 + kc*16 + (wave*2+s)) * 64 + lane];
    }
  {
    int fb4 = (wave < 4) ? FB_WU2 : FB_WR2;
    int mt4 = wave & 3;
#pragma unroll
    for (int kc = 0; kc < 8; ++kc) {
      cw4[2*kc]   = WF[(fb4 + kc*4 + mt4) * 64 + lane];
      cw4[2*kc+1] = WF[(NFRAGS + fb4 + kc*4 + mt4) * 64 + lane];
      cw6[2*kc]   = WF[(FB_WN2 + kc*8 + wave) * 64 + lane];
      cw6[2*kc+1] = WF[(NFRAGS + FB_WN2 + kc*8 + wave) * 64 + lane];
    }
  }
#pragma unroll
  for (int i = 0; i < 8; ++i)  KEEP(cw1[i]);
#pragma unroll
  for (int i = 0; i < 16; ++i) { KEEP(cw4[i]); KEEP(cw6[i]); }

  // ---- stage Wo2 into LDS (64 frags x 64 lanes x 16B) ----
  for (int i = tid; i < 64*64; i += 512) {
    int idx = i >> 6, l = i & 63;
    int src = (idx < 32) ? (FB_WO2 + idx) : (NFRAGS + FB_WO2 + (idx - 32));
    l_wo2[i] = WF[src * 64 + l];
  }

  // stage biases / dts, zero state
  for (int i = tid; i < NU; i += 512) s_bias[0    + i] = bo1[i];
  if (tid < LD)                       s_bias[256  + tid] = bo2[tid];
  for (int i = tid; i < NU; i += 512) s_bias[320  + i] = bu1[i];
  if (tid < LD)                       s_bias[576  + tid] = bu2[tid];
  for (int i = tid; i < NU; i += 512) s_bias[640  + i] = br1[i];
  if (tid < LD)                       s_bias[896  + tid] = br2[tid];
  for (int i = tid; i < NU; i += 512) s_bias[960  + i] = bn1[i];
  if (tid < 2*LD)                     s_bias[1216 + tid] = bn2[tid];
  if (tid < LSTEPS-1) s_dts[tid] = (tid == 0) ? (ts[1] - ts[0]) : (ts[tid] - ts[tid+1]);
  for (int i = tid; i < MB*PF;  i += 512) { s_y[i] = 0.f; s_lv[i] = 0.f; }
  for (int i = tid; i < 2*MB*PBY; i += 512) {
    ((_Float16*)b_y)[i]  = (_Float16)0.f;
    ((_Float16*)b_lv)[i] = (_Float16)0.f;
  }
  __syncthreads();

  for (int t = 0; t < LSTEPS-1; ++t) {
    // ---- S1: hid_o = tanh(Wo1^T y + bo1); cached cw1; 2 mtiles/wave; 2-chain ILP ----
    {
      f16x8 b0h = LDB(b_y[0],PBY,0),  b0l = LDB(b_y[1],PBY,0);
      f16x8 b1h = LDB(b_y[0],PBY,32), b1l = LDB(b_y[1],PBY,32);
#pragma unroll
      for (int s = 0; s < 2; ++s) {
        f32x4 aH = {0.f,0.f,0.f,0.f}, aL = {0.f,0.f,0.f,0.f};
        aH = MFMA(cw1[4*s],   b0h, aH);
        aL = MFMA(cw1[4*s+1], b0h, aL);
        aL = MFMA(cw1[4*s],   b0l, aL);
        aH = MFMA(cw1[4*s+2], b1h, aH);
        aL = MFMA(cw1[4*s+3], b1h, aL);
        aL = MFMA(cw1[4*s+2], b1l, aL);
        f32x4 acc = aH + aL;
        int f0 = (wave*2+s)*16 + q*4;
        f32x4 bb = *(const f32x4*)&s_bias[0 + f0];
        f16x4 hv, lv4;
#pragma unroll
        for (int r = 0; r < 4; ++r) {
          f16x2 sp = split2(tanh_fast(acc[r] + bb[r]));
          hv[r] = sp[0]; lv4[r] = sp[1];
        }
        *(f16x4*)&b_hid[0][l16*PBH + f0] = hv;
        *(f16x4*)&b_hid[1][l16*PBH + f0] = lv4;
      }
    }
    __syncthreads();

    // ---- S2: yode = y + dt*(Wo2^T hid_o + bo2); waves 0-3 (Wo2 in LDS); 3-chain ILP ----
    if (wave < 4) {
      float dt = s_dts[t];
      f32x4 aA = {0.f,0.f,0.f,0.f}, aB = {0.f,0.f,0.f,0.f}, aC = {0.f,0.f,0.f,0.f};
#pragma unroll
      for (int kc = 0; kc < 8; ++kc) {
        f16x8 ah = l_wo2[(kc*4 + wave)*64 + lane];
        f16x8 al = l_wo2[(32 + kc*4 + wave)*64 + lane];
        f16x8 bhk = LDB(b_hid[0],PBH,kc*32), blk = LDB(b_hid[1],PBH,kc*32);
        aA = MFMA(ah, bhk, aA);
        aB = MFMA(al, bhk, aB);
        aC = MFMA(ah, blk, aC);
      }
      f32x4 acc = aA + aB + aC;
      int f0 = wave*16 + q*4;
      f32x4 bb = *(const f32x4*)&s_bias[256 + f0];
      f32x4 yv = *(const f32x4*)&s_y[l16*PF + f0];
      f32x4 yo;
      f16x4 hv, lv4;
#pragma unroll
      for (int r = 0; r < 4; ++r) {
        yo[r] = yv[r] + dt * (acc[r] + bb[r]);
        f16x2 sp = split2(yo[r]);
        hv[r] = sp[0]; lv4[r] = sp[1];
      }
      *(f32x4*)&s_yode[l16*PF + f0] = yo;
      *(f16x4*)&b_yode[0][l16*PBY + f0] = hv;
      *(f16x4*)&b_yode[1][l16*PBY + f0] = lv4;
    } else {
      int idx = tid - 256;                 // 0..255: 16 rows x 16 thread-cols x 2 elems
      int row = idx >> 4, c0 = (idx & 15) * 2;
      f32x2 d = *(const f32x2*)&data[(size_t)(traj0 + row) * LSTEPS * IDIM
                                     + (size_t)(t+1) * IDIM + c0];
      f16x2 s0 = split2(d[0]), s1 = split2(d[1]);
      f16x2 xh, xl;
      xh[0] = s0[0]; xl[0] = s0[1];
      xh[1] = s1[0]; xl[1] = s1[1];
      *(f16x2*)&b_x[0][row*PBX + c0] = xh;
      *(f16x2*)&b_x[1][row*PBX + c0] = xl;
    }
    __syncthreads();

    // ---- S3: hid_ur = tanh([Wu1|Wr1]^T yc + b); s-outer (low liveness), 2-chain ILP ----
    {
      f16x8 bh[5], bl[5];
      bh[0] = LDB(b_yode[0],PBY,0);  bl[0] = LDB(b_yode[1],PBY,0);
      bh[1] = LDB(b_yode[0],PBY,32); bl[1] = LDB(b_yode[1],PBY,32);
      bh[2] = LDB(b_lv[0],  PBY,0);  bl[2] = LDB(b_lv[1],  PBY,0);
      bh[3] = LDB(b_lv[0],  PBY,32); bl[3] = LDB(b_lv[1],  PBY,32);
      bh[4] = LDB(b_x[0],   PBX,0);  bl[4] = LDB(b_x[1],   PBX,0);
      int isR = wave >> 2;
      int fb  = isR ? FB_WR1 : FB_WU1;
#pragma unroll
      for (int s = 0; s < 4; ++s) {
        int mt = (wave & 3)*4 + s;            // 0..15 within gate
        f32x4 aH = {0.f,0.f,0.f,0.f}, aL = {0.f,0.f,0.f,0.f};
#pragma unroll
        for (int kc = 0; kc < 5; ++kc) {
          f16x8 ah = AH(fb,16,kc,mt);
          f16x8 al = AL(fb,16,kc,mt);
          aH = MFMA(ah, bh[kc], aH);
          aL = MFMA(al, bh[kc], aL);
          aL = MFMA(ah, bl[kc], aL);
        }
        f32x4 acc = aH + aL;
        int col0 = mt*16 + q*4;               // 0..255 within gate
        f32x4 bb = *(const f32x4*)&s_bias[(isR ? 640 : 320) + col0];
        int dcol = (isR ? 256 : 0) + col0;
        f16x4 hv, lv4;
#pragma unroll
        for (int r = 0; r < 4; ++r) {
          f16x2 sp = split2(tanh_fast(acc[r] + bb[r]));
          hv[r] = sp[0]; lv4[r] = sp[1];
        }
        *(f16x4*)&b_hid[0][l16*PBH + dcol] = hv;
        *(f16x4*)&b_hid[1][l16*PBH + dcol] = lv4;
      }
    }
    __syncthreads();

    // ---- S4: U = sig(Wu2^T hid_u), R = sig(Wr2^T hid_r); cached cw4; 3-chain; cc fused ----
    {
      int isR  = wave >> 2;
      int aofs = isR ? 256 : 0;
      f32x4 aA = {0.f,0.f,0.f,0.f}, aB = {0.f,0.f,0.f,0.f}, aC = {0.f,0.f,0.f,0.f};
#pragma unroll
      for (int kc = 0; kc < 8; ++kc) {
        f16x8 bhk = LDB(b_hid[0],PBH,aofs+kc*32), blk = LDB(b_hid[1],PBH,aofs+kc*32);
        aA = MFMA(cw4[2*kc],   bhk, aA);
        aB = MFMA(cw4[2*kc+1], bhk, aB);
        aC = MFMA(cw4[2*kc],   blk, aC);
      }
      f32x4 acc = aA + aB + aC;
      int f0 = (wave & 3)*16 + q*4;
      f32x4 bb = *(const f32x4*)&s_bias[(isR ? 896 : 576) + f0];
      if (!isR) {
        f32x4 o;
#pragma unroll
        for (int r = 0; r < 4; ++r) o[r] = sigmoid_fast(acc[r] + bb[r]);
        *(f32x4*)&s_U[l16*PF + f0] = o;
      } else {
        // R never materialized: build cc = [yode*R | lv*R] directly
        f32x4 yo = *(const f32x4*)&s_yode[l16*PF + f0];
        f32x4 lv = *(const f32x4*)&s_lv[l16*PF + f0];
        f16x4 yh, yl, lh, ll;
#pragma unroll
        for (int r = 0; r < 4; ++r) {
          float rv = sigmoid_fast(acc[r] + bb[r]);
          f16x2 sa = split2(yo[r] * rv);
          f16x2 sb = split2(lv[r] * rv);
          yh[r] = sa[0]; yl[r] = sa[1];
          lh[r] = sb[0]; ll[r] = sb[1];
        }
        *(f16x4*)&b_cc[0][l16*PBC + f0] = yh;
        *(f16x4*)&b_cc[1][l16*PBC + f0] = yl;
        *(f16x4*)&b_cc[0][l16*PBC + 64 + f0] = lh;
        *(f16x4*)&b_cc[1][l16*PBC + 64 + f0] = ll;
      }
    }
    __syncthreads();

    // ---- S5: hid_n = tanh(Wn1^T cc + bn1); s-outer, 2-chain ILP ----
    {
      f16x8 bh[5], bl[5];
      bh[0] = LDB(b_cc[0],PBC,0);  bl[0] = LDB(b_cc[1],PBC,0);
      bh[1] = LDB(b_cc[0],PBC,32); bl[1] = LDB(b_cc[1],PBC,32);
      bh[2] = LDB(b_cc[0],PBC,64); bl[2] = LDB(b_cc[1],PBC,64);
      bh[3] = LDB(b_cc[0],PBC,96); bl[3] = LDB(b_cc[1],PBC,96);
      bh[4] = LDB(b_x[0], PBX,0);  bl[4] = LDB(b_x[1], PBX,0);
#pragma unroll
      for (int s = 0; s < 2; ++s) {
        int mt = wave*2 + s;
        f32x4 aH = {0.f,0.f,0.f,0.f}, aL = {0.f,0.f,0.f,0.f};
#pragma unroll
        for (int kc = 0; kc < 5; ++kc) {
          f16x8 ah = AH(FB_WN1,16,kc,mt);
          f16x8 al = AL(FB_WN1,16,kc,mt);
          aH = MFMA(ah, bh[kc], aH);
          aL = MFMA(al, bh[kc], aL);
          aL = MFMA(ah, bl[kc], aL);
        }
        f32x4 acc = aH + aL;
        int f0 = mt*16 + q*4;
        f32x4 bb = *(const f32x4*)&s_bias[960 + f0];
        f16x4 hv, lv4;
#pragma unroll
        for (int r = 0; r < 4; ++r) {
          f16x2 sp = split2(tanh_fast(acc[r] + bb[r]));
          hv[r] = sp[0]; lv4[r] = sp[1];
        }
        *(f16x4*)&b_hid[0][l16*PBH + f0] = hv;
        *(f16x4*)&b_hid[1][l16*PBH + f0] = lv4;
      }
    }
    __syncthreads();

    // ---- S6: h = Wn2^T hid_n + bn2; GRU gating + state update; cached cw6; 3-chain ----
    {
      f32x4 aA = {0.f,0.f,0.f,0.f}, aB = {0.f,0.f,0.f,0.f}, aC = {0.f,0.f,0.f,0.f};
#pragma unroll
      for (int kc = 0; kc < 8; ++kc) {
        f16x8 bhk = LDB(b_hid[0],PBH,kc*32), blk = LDB(b_hid[1],PBH,kc*32);
        aA = MFMA(cw6[2*kc],   bhk, aA);
        aB = MFMA(cw6[2*kc+1], bhk, aB);
        aC = MFMA(cw6[2*kc],   blk, aC);
      }
      f32x4 acc = aA + aB + aC;
      int f0 = wave*16 + q*4;                      // 0..127
      f32x4 bb = *(const f32x4*)&s_bias[1216 + f0];
      if (wave < 4) {
        f32x4 u  = *(const f32x4*)&s_U[l16*PF + f0];
        f32x4 yo = *(const f32x4*)&s_yode[l16*PF + f0];
        f32x4 nv;
        f16x4 hv, lv4;
#pragma unroll
        for (int r = 0; r < 4; ++r) {
          float h = acc[r] + bb[r];
          nv[r] = (1.f - u[r]) * h + u[r] * yo[r];
          f16x2 sp = split2(nv[r]);
          hv[r] = sp[0]; lv4[r] = sp[1];
        }
        *(f32x4*)&s_y[l16*PF + f0] = nv;
        *(f16x4*)&b_y[0][l16*PBY + f0] = hv;
        *(f16x4*)&b_y[1][l16*PBY + f0] = lv4;
      } else {
        int f2 = f0 - 64;
        f32x4 u  = *(const f32x4*)&s_U[l16*PF + f2];
        f32x4 lv = *(const f32x4*)&s_lv[l16*PF + f2];
        f32x4 nl;
        f16x4 hv, lv4;
#pragma unroll
        for (int r = 0; r < 4; ++r) {
          float h = fabsf(acc[r] + bb[r]);
          nl[r] = (1.f - u[r]) * h + u[r] * lv[r];
          f16x2 sp = split2(nl[r]);
          hv[r] = sp[0]; lv4[r] = sp[1];
        }
        *(f32x4*)&s_lv[l16*PF + f2] = nl;
        *(f16x4*)&b_lv[0][l16*PBY + f2] = hv;
        *(f16x4*)&b_lv[1][l16*PBY + f2] = lv4;
      }
    }
    __syncthreads();
  }

  // write outputs: (yi, yi_logvar) concatenated
  for (int i = tid; i < MB*LD; i += 512) {
    int row = i >> 6, c = i & 63;
    out[(size_t)(traj0 + row) * LD + c] = s_y[row*PF + c];
    out[(size_t)NTRAJ * LD + (size_t)(traj0 + row) * LD + c] = s_lv[row*PF + c];
  }
}

extern "C" void kernel_launch(void* const* d_in, const int* in_sizes, int n_in,
                              void* d_out, int out_size, void* d_ws, size_t ws_size,
                              hipStream_t stream) {
  const float* data = (const float*)d_in[0];
  const float* ts   = (const float*)d_in[1];
  const float* Wo1  = (const float*)d_in[2];  const float* bo1 = (const float*)d_in[3];
  const float* Wo2  = (const float*)d_in[4];  const float* bo2 = (const float*)d_in[5];
  const float* Wu1  = (const float*)d_in[6];  const float* bu1 = (const float*)d_in[7];
  const float* Wu2  = (const float*)d_in[8];  const float* bu2 = (const float*)d_in[9];
  const float* Wr1  = (const float*)d_in[10]; const float* br1 = (const float*)d_in[11];
  const float* Wr2  = (const float*)d_in[12]; const float* br2 = (const float*)d_in[13];
  const float* Wn1  = (const float*)d_in[14]; const float* bn1 = (const float*)d_in[15];
  const float* Wn2  = (const float*)d_in[16]; const float* bn2 = (const float*)d_in[17];

  prep_weights<<<NFRAGS, 64, 0, stream>>>(Wo1, Wo2, Wu1, Wu2, Wr1, Wr2, Wn1, Wn2,
                                          (f16x8*)d_ws);
  vae_main<<<NBLK, 512, 0, stream>>>(data, ts, bo1, bo2, bu1, bu2, br1, br2,
                                     bn1, bn2, (const f16x8*)d_ws, (float*)d_out);
}